// Round 1
// baseline (179.156 us; speedup 1.0000x reference)
//
#include <hip/hip_runtime.h>
#include <stdint.h>

#define S_LEN 2048
#define D_DIM 64
#define NBH   32
#define TQ    128
#define KT    64
#define SCALE_F 0.125f
#define EPS_F   1e-6f

typedef __attribute__((ext_vector_type(8))) short bf8_t;
typedef __attribute__((ext_vector_type(4))) float f4_t;

#define MFMA16(a,b,c) __builtin_amdgcn_mfma_f32_16x16x32_bf16((a),(b),(c),0,0,0)

__device__ __forceinline__ unsigned short f2bf(float f) {
  union { float f; unsigned int u; } x; x.f = f;
  unsigned int r = x.u + 0x7fffu + ((x.u >> 16) & 1u);
  return (unsigned short)(r >> 16);
}

// ---------------- G = K^T K (64x64 per bh) ----------------
__global__ __launch_bounds__(256) void g_kernel(const float* __restrict__ kp,
                                                float* __restrict__ g) {
  __shared__ __align__(16) float sk[64][68];
  const int bh = blockIdx.x >> 3, rc = blockIdx.x & 7;
  const int t = threadIdx.x;
  const int ti = t & 15, tj = t >> 4;
  float acc[4][4];
#pragma unroll
  for (int a = 0; a < 4; ++a)
#pragma unroll
    for (int b = 0; b < 4; ++b) acc[a][b] = 0.f;
  const float* kb = kp + ((size_t)bh * S_LEN + rc * 256) * D_DIM;
  for (int sub = 0; sub < 4; ++sub) {
    __syncthreads();
    {
      const int r = t >> 2, c0 = (t & 3) * 16;
      const float4* p = (const float4*)(kb + (size_t)(sub * 64 + r) * D_DIM + c0);
      float4 x0 = p[0], x1 = p[1], x2 = p[2], x3 = p[3];
      *(float4*)&sk[r][c0]      = x0;
      *(float4*)&sk[r][c0 + 4]  = x1;
      *(float4*)&sk[r][c0 + 8]  = x2;
      *(float4*)&sk[r][c0 + 12] = x3;
    }
    __syncthreads();
#pragma unroll 4
    for (int r = 0; r < 64; ++r) {
      float4 qi = *(const float4*)&sk[r][ti * 4];
      float4 qj = *(const float4*)&sk[r][tj * 4];
      float iv[4] = {qi.x, qi.y, qi.z, qi.w};
      float jv[4] = {qj.x, qj.y, qj.z, qj.w};
#pragma unroll
      for (int a = 0; a < 4; ++a)
#pragma unroll
        for (int b = 0; b < 4; ++b) acc[a][b] += iv[a] * jv[b];
    }
  }
  float* gb = g + ((size_t)bh << 12);
#pragma unroll
  for (int a = 0; a < 4; ++a)
#pragma unroll
    for (int b = 0; b < 4; ++b)
      atomicAdd(&gb[(ti * 4 + a) * 64 + tj * 4 + b], acc[a][b]);
}

// ---------------- staging helpers ----------------
// 64x64 f32 tile -> bf16 LDS tile, rows 64 shorts, XOR-swizzled 16B chunks.
__device__ __forceinline__ void stage_swz(unsigned short* dst, const float* src, int t) {
  const int r = t >> 3, cg = t & 7;
  const float4* p = (const float4*)(src + (size_t)r * D_DIM + cg * 8);
  float4 a = p[0], b = p[1];
  bf8_t vv;
  vv[0] = (short)f2bf(a.x); vv[1] = (short)f2bf(a.y);
  vv[2] = (short)f2bf(a.z); vv[3] = (short)f2bf(a.w);
  vv[4] = (short)f2bf(b.x); vv[5] = (short)f2bf(b.y);
  vv[6] = (short)f2bf(b.z); vv[7] = (short)f2bf(b.w);
  *(bf8_t*)(dst + r * 64 + ((cg ^ (r & 7)) << 3)) = vv;
}

__device__ __forceinline__ bf8_t frag_swz(const unsigned short* sp, int row, int cb) {
  return *(const bf8_t*)(sp + row * 64 + ((cb ^ (row & 7)) << 3));
}

// V[kv][d] -> Vt[d][kv] bf16, rows stride 72 shorts. Strided-d ownership keeps
// LDS writes 2-way (free) and register indexing static.
__device__ __forceinline__ void stage_vt(unsigned short* dst, const float* src, int t) {
  const int kv = t >> 3, dg = t & 7;
  const float* vp = src + (size_t)kv * D_DIM + dg;
#pragma unroll
  for (int j = 0; j < 8; ++j) {
    dst[(dg + 8 * j) * 72 + kv] = f2bf(vp[8 * j]);
  }
}

// ---------------- main attention kernel ----------------
__global__ __launch_bounds__(512) void attn_main(const float* __restrict__ q,
                                                 const float* __restrict__ k,
                                                 const float* __restrict__ v,
                                                 const float* __restrict__ g,
                                                 float* __restrict__ outp,
                                                 float* __restrict__ probp) {
  __shared__ __align__(16) unsigned short sK[64 * 64];
  __shared__ __align__(16) unsigned short sVt[64 * 72];
  __shared__ __align__(16) unsigned short sP[8 * 16 * 72];

  // XCD-aware swizzle: each XCD gets 64 consecutive virtual block ids (4 bh's).
  const int lin = blockIdx.x;
  const int virt = (lin & 7) * 64 + (lin >> 3);
  const int bh = virt >> 4, qb = virt & 15;
  const int q0 = qb * TQ;
  const int t = threadIdx.x, lane = t & 63, w = t >> 6;
  const int lr = lane & 15, lh = lane >> 4;

  // Q A-fragments (scale folded in): lane holds Q[q0+w*16+lr][h2*32+lh*8 .. +7]
  bf8_t qA[2];
  {
    const float* qbase = q + ((size_t)bh * S_LEN + q0 + w * 16 + lr) * D_DIM;
#pragma unroll
    for (int h2 = 0; h2 < 2; ++h2) {
      const float4* qp = (const float4*)(qbase + h2 * 32 + lh * 8);
      float4 a = qp[0], b = qp[1];
      bf8_t vv;
      vv[0] = (short)f2bf(a.x * SCALE_F); vv[1] = (short)f2bf(a.y * SCALE_F);
      vv[2] = (short)f2bf(a.z * SCALE_F); vv[3] = (short)f2bf(a.w * SCALE_F);
      vv[4] = (short)f2bf(b.x * SCALE_F); vv[5] = (short)f2bf(b.y * SCALE_F);
      vv[6] = (short)f2bf(b.z * SCALE_F); vv[7] = (short)f2bf(b.w * SCALE_F);
      qA[h2] = vv;
    }
  }

  // ---- den[q] = c^2 q^T G q via MFMA (G symmetric => row-contig B-frags) ----
  stage_swz(sK, g + ((size_t)bh << 12), t);
  __syncthreads();
  float inv[4];
  {
    float den[4] = {0.f, 0.f, 0.f, 0.f};
#pragma unroll
    for (int ct = 0; ct < 4; ++ct) {
      f4_t accT = {0.f, 0.f, 0.f, 0.f};
      bf8_t b0 = frag_swz(sK, ct * 16 + lr, lh);
      bf8_t b1 = frag_swz(sK, ct * 16 + lr, 4 + lh);
      accT = MFMA16(qA[0], b0, accT);
      accT = MFMA16(qA[1], b1, accT);
#pragma unroll
      for (int i = 0; i < 4; ++i) {
        float qv = q[((size_t)bh * S_LEN + q0 + w * 16 + lh * 4 + i) * D_DIM + ct * 16 + lr] * SCALE_F;
        den[i] += accT[i] * qv;
      }
    }
#pragma unroll
    for (int i = 0; i < 4; ++i) {
      den[i] += __shfl_xor(den[i], 1, 64);
      den[i] += __shfl_xor(den[i], 2, 64);
      den[i] += __shfl_xor(den[i], 4, 64);
      den[i] += __shfl_xor(den[i], 8, 64);
      inv[i] = 1.f / (den[i] + EPS_F);
    }
  }
  __syncthreads();

  // ---- main K/V sweep ----
  f4_t oacc[4];
#pragma unroll
  for (int dt = 0; dt < 4; ++dt)
#pragma unroll
    for (int i = 0; i < 4; ++i) oacc[dt][i] = 0.f;

  const float* kbh = k + (size_t)bh * S_LEN * D_DIM;
  const float* vbh = v + (size_t)bh * S_LEN * D_DIM;
  unsigned short* sPw = sP + w * (16 * 72);
  float* probw = probp + ((size_t)bh * S_LEN + q0 + w * 16) * S_LEN;

  for (int kt = 0; kt < S_LEN / KT; ++kt) {
    const int k0 = kt * KT;
    stage_swz(sK, kbh + (size_t)k0 * D_DIM, t);
    stage_vt(sVt, vbh + (size_t)k0 * D_DIM, t);
    __syncthreads();

    // QK^T -> prob (fp32 to global, bf16 to per-wave LDS tile)
#pragma unroll
    for (int ct = 0; ct < 4; ++ct) {
      f4_t acc = {0.f, 0.f, 0.f, 0.f};
      bf8_t b0 = frag_swz(sK, ct * 16 + lr, lh);
      bf8_t b1 = frag_swz(sK, ct * 16 + lr, 4 + lh);
      acc = MFMA16(qA[0], b0, acc);
      acc = MFMA16(qA[1], b1, acc);
#pragma unroll
      for (int i = 0; i < 4; ++i) {
        float pv_ = acc[i] * acc[i] * inv[i];
        __builtin_nontemporal_store(pv_, probw + (size_t)(lh * 4 + i) * S_LEN + k0 + ct * 16 + lr);
        sPw[(lh * 4 + i) * 72 + ct * 16 + lr] = f2bf(pv_);
      }
    }

    // PV: out += prob(bf16) @ V
#pragma unroll
    for (int ks = 0; ks < 2; ++ks) {
      bf8_t pa = *(const bf8_t*)(sPw + lr * 72 + ks * 32 + lh * 8);
#pragma unroll
      for (int dt = 0; dt < 4; ++dt) {
        bf8_t vb = *(const bf8_t*)(sVt + (dt * 16 + lr) * 72 + ks * 32 + lh * 8);
        oacc[dt] = MFMA16(pa, vb, oacc[dt]);
      }
    }
    __syncthreads();
  }

  float* ob = outp + ((size_t)bh * S_LEN + q0 + w * 16) * D_DIM;
#pragma unroll
  for (int dt = 0; dt < 4; ++dt)
#pragma unroll
    for (int i = 0; i < 4; ++i)
      __builtin_nontemporal_store(oacc[dt][i], ob + (size_t)(lh * 4 + i) * D_DIM + dt * 16 + lr);
}

extern "C" void kernel_launch(void* const* d_in, const int* in_sizes, int n_in,
                              void* d_out, int out_size, void* d_ws, size_t ws_size,
                              hipStream_t stream) {
  (void)in_sizes; (void)n_in; (void)out_size; (void)ws_size;
  const float* q = (const float*)d_in[0];
  const float* k = (const float*)d_in[1];
  const float* v = (const float*)d_in[2];
  float* outp  = (float*)d_out;
  float* probp = outp + (size_t)NBH * S_LEN * D_DIM;
  float* g = (float*)d_ws;

  hipMemsetAsync(g, 0, (size_t)NBH * 64 * 64 * sizeof(float), stream);
  g_kernel<<<dim3(NBH * 8), dim3(256), 0, stream>>>(k, g);
  attn_main<<<dim3(512), dim3(512), 0, stream>>>(q, k, v, g, outp, probp);
}